// Round 3
// baseline (126.447 us; speedup 1.0000x reference)
//
#include <hip/hip_runtime.h>
#include <hip/hip_fp16.h>

#define NQ 4096
#define NH 8
#define ND 32
#define NK 30720   // 16384+8192+4096+2048
#define LDSS 33    // padded LDS row stride (conflict-free writes+reads)

// ---- Pre-pass: value fp32 -> fp16 into workspace (halves gather traffic) ----
__global__ __launch_bounds__(256) void cvt_kernel(const float* __restrict__ v,
                                                  uint4* __restrict__ o, int n8) {
    int i = blockIdx.x * blockDim.x + threadIdx.x;
    const float4* __restrict__ v4 = (const float4*)v;
    for (; i < n8; i += gridDim.x * blockDim.x) {
        const float4 f0 = v4[2 * i];
        const float4 f1 = v4[2 * i + 1];
        __half2 h0 = __floats2half2_rn(f0.x, f0.y);
        __half2 h1 = __floats2half2_rn(f0.z, f0.w);
        __half2 h2 = __floats2half2_rn(f1.x, f1.y);
        __half2 h3 = __floats2half2_rn(f1.z, f1.w);
        uint4 u;
        u.x = *reinterpret_cast<unsigned*>(&h0);
        u.y = *reinterpret_cast<unsigned*>(&h1);
        u.z = *reinterpret_cast<unsigned*>(&h2);
        u.w = *reinterpret_cast<unsigned*>(&h3);
        o[i] = u;
    }
}

// Block = 256 threads handles 4 consecutive queries of one batch.
// Phase 1: per-block sample descriptors packed into LDS (kk: k1|k2<<16, ww: half2).
// Phase 2: thread = (qi, h, d4); gathers batched 8 taps at a time for MLP.
template <bool FP16>
__global__ __launch_bounds__(256, 6) void spd_kernel(
    const float* __restrict__ value,   // (bs, NK, H, D) fp32
    const __half* __restrict__ vh,     // same, fp16 (workspace), if FP16
    const float* __restrict__ loc,     // (bs, NQ, H, LV, P, 1)
    const float* __restrict__ wts,     // (bs, NQ, H, LV, P)
    float* __restrict__ out)           // (bs, NQ, H*D)
{
    const int tid = threadIdx.x;
    // XCD swizzle: XCD = launched bid % 8; give each XCD one batch's chunk.
    const int vbid = ((blockIdx.x & 7) << 9) | (blockIdx.x >> 3);
    const int bq0 = vbid << 2;                // first flat (b*NQ + q)
    const int b   = bq0 >> 12;                // NQ = 4096

    __shared__ unsigned s_kk[32 * LDSS];      // k1 | k2<<16
    __shared__ unsigned s_ww[32 * LDSS];      // half2(w1, w2)

    // ---- Phase 1: precompute sample descriptors ----
    #pragma unroll
    for (int e = 0; e < 4; ++e) {
        const int ent = (e << 8) | tid;       // ent = qi*256 + h*32 + l*8 + p
        const size_t g = (size_t)bq0 * 256 + (size_t)ent;
        const float x_loc = loc[g];
        const float w     = wts[g];

        const int l   = (ent >> 3) & 3;
        const int L   = 16384 >> l;
        const int off = 32768 - (32768 >> l); // 0, 16384, 24576, 28672

        const float x  = x_loc * (float)L - 1.0f;
        const float xf = floorf(x);
        const float lx = x - xf;
        const float hx = 1.0f - lx;
        const int   xl = (int)xf;
        const int   xh = xl + 1;

        const bool ok1 = (xl >= 0) && (xl < L);
        const bool ok2 = (xh >= 0) && (xh < L);
        int c1 = xl < 0 ? 0 : (xl > L - 1 ? L - 1 : xl);
        int c2 = xh < 0 ? 0 : (xh > L - 1 ? L - 1 : xh);
        const float w1 = ok1 ? w * hx : 0.0f;
        const float w2 = ok2 ? w * lx : 0.0f;

        // row = l*8+p (j), col = qi*8+h ; stride 33 -> conflict-free
        const int li = (ent & 31) * LDSS + ((((ent >> 8) & 3) << 3) | ((ent >> 5) & 7));
        s_kk[li] = (unsigned)(off + c1) | ((unsigned)(off + c2) << 16);
        __half2 wh = __floats2half2_rn(w1, w2);
        s_ww[li] = *reinterpret_cast<unsigned*>(&wh);
    }
    __syncthreads();

    // ---- Phase 2: batched gather + accumulate ----
    const int qi = tid >> 6;         // query within block (one wave per query)
    const int h  = (tid >> 3) & 7;
    const int d4 = tid & 7;          // float4/uint2 slice of D=32
    const int cb = (qi << 3) | h;
    const unsigned lane = (unsigned)((h << 3) | d4);

    float4 acc = make_float4(0.f, 0.f, 0.f, 0.f);

    if (FP16) {
        const uint2* __restrict__ vb2 =
            (const uint2*)(vh + (size_t)b * (NK * NH * ND));   // per-batch base
        #pragma unroll 1
        for (int jj = 0; jj < 32; jj += 8) {
            unsigned ww[8];
            uint2 r1[8], r2[8];
            #pragma unroll
            for (int u = 0; u < 8; ++u) {
                const int li = (jj + u) * LDSS + cb;
                const unsigned kk = s_kk[li];
                ww[u] = s_ww[li];
                r1[u] = vb2[(kk & 0xffffu) * 64u + lane];
                r2[u] = vb2[(kk >> 16) * 64u + lane];
            }
            #pragma unroll
            for (int u = 0; u < 8; ++u) {
                const __half2 wh = *reinterpret_cast<const __half2*>(&ww[u]);
                const float w1 = __low2float(wh);
                const float w2 = __high2float(wh);
                const float2 a0 = __half22float2(*(const __half2*)&r1[u].x);
                const float2 a1 = __half22float2(*(const __half2*)&r1[u].y);
                const float2 c0 = __half22float2(*(const __half2*)&r2[u].x);
                const float2 c1 = __half22float2(*(const __half2*)&r2[u].y);
                acc.x += w1 * a0.x + w2 * c0.x;
                acc.y += w1 * a0.y + w2 * c0.y;
                acc.z += w1 * a1.x + w2 * c1.x;
                acc.w += w1 * a1.y + w2 * c1.y;
            }
        }
    } else {
        const float4* __restrict__ vb4 =
            (const float4*)(value) + (size_t)b * (NK * 64);
        #pragma unroll 1
        for (int jj = 0; jj < 32; jj += 4) {
            unsigned ww[4];
            float4 r1[4], r2[4];
            #pragma unroll
            for (int u = 0; u < 4; ++u) {
                const int li = (jj + u) * LDSS + cb;
                const unsigned kk = s_kk[li];
                ww[u] = s_ww[li];
                r1[u] = vb4[(size_t)(kk & 0xffffu) * 64 + lane];
                r2[u] = vb4[(size_t)(kk >> 16) * 64 + lane];
            }
            #pragma unroll
            for (int u = 0; u < 4; ++u) {
                const __half2 wh = *reinterpret_cast<const __half2*>(&ww[u]);
                const float w1 = __low2float(wh);
                const float w2 = __high2float(wh);
                acc.x += w1 * r1[u].x + w2 * r2[u].x;
                acc.y += w1 * r1[u].y + w2 * r2[u].y;
                acc.z += w1 * r1[u].z + w2 * r2[u].z;
                acc.w += w1 * r1[u].w + w2 * r2[u].w;
            }
        }
    }

    float4* __restrict__ o4 = (float4*)out;
    o4[(size_t)(bq0 + qi) * 64 + ((h << 3) | d4)] = acc;
}

extern "C" void kernel_launch(void* const* d_in, const int* in_sizes, int n_in,
                              void* d_out, int out_size, void* d_ws, size_t ws_size,
                              hipStream_t stream) {
    const float* value = (const float*)d_in[0];
    const float* loc   = (const float*)d_in[1];
    const float* wts   = (const float*)d_in[2];
    float* out = (float*)d_out;

    const int bs = 4;
    const int blocks = bs * NQ / 4;   // 4096
    const size_t need = (size_t)bs * NK * NH * ND * sizeof(__half);  // ~63 MB

    if (ws_size >= need) {
        const int n8 = bs * NK * NH * ND / 8;  // 8 floats per thread-iter
        cvt_kernel<<<4096, 256, 0, stream>>>(value, (uint4*)d_ws, n8);
        spd_kernel<true><<<blocks, 256, 0, stream>>>(value, (const __half*)d_ws,
                                                     loc, wts, out);
    } else {
        spd_kernel<false><<<blocks, 256, 0, stream>>>(value, nullptr,
                                                      loc, wts, out);
    }
}

// Round 4
// 126.427 us; speedup vs baseline: 1.0002x; 1.0002x over previous
//
#include <hip/hip_runtime.h>
#include <hip/hip_fp16.h>

#define NQ 4096
#define NH 8
#define ND 32
#define NK 30720   // 16384+8192+4096+2048
#define LDSS 33    // padded LDS row stride (conflict-free)

// ---- Pre-pass: value fp32 -> fp16 into workspace (halves gather traffic) ----
__global__ __launch_bounds__(256) void cvt_kernel(const float* __restrict__ v,
                                                  uint4* __restrict__ o, int n8) {
    int i = blockIdx.x * blockDim.x + threadIdx.x;
    const float4* __restrict__ v4 = (const float4*)v;
    for (; i < n8; i += gridDim.x * blockDim.x) {
        const float4 f0 = v4[2 * i];
        const float4 f1 = v4[2 * i + 1];
        __half2 h0 = __floats2half2_rn(f0.x, f0.y);
        __half2 h1 = __floats2half2_rn(f0.z, f0.w);
        __half2 h2 = __floats2half2_rn(f1.x, f1.y);
        __half2 h3 = __floats2half2_rn(f1.z, f1.w);
        uint4 u;
        u.x = *reinterpret_cast<unsigned*>(&h0);
        u.y = *reinterpret_cast<unsigned*>(&h1);
        u.z = *reinterpret_cast<unsigned*>(&h2);
        u.w = *reinterpret_cast<unsigned*>(&h3);
        o[i] = u;
    }
}

__device__ __forceinline__ void load4(const uint2* __restrict__ vb2,
                                      const uint2* s_d, int jj, int cb,
                                      unsigned lane, unsigned* w,
                                      uint2* ra, uint2* rb) {
    #pragma unroll
    for (int u = 0; u < 4; ++u) {
        const uint2 d = s_d[(jj + u) * LDSS + cb];
        w[u]  = d.y;
        ra[u] = vb2[((d.x & 0xffffu) << 6) + lane];
        rb[u] = vb2[((d.x >> 16) << 6) + lane];
    }
}

__device__ __forceinline__ void consume4(const unsigned* w, const uint2* ra,
                                         const uint2* rb, float4& acc) {
    #pragma unroll
    for (int u = 0; u < 4; ++u) {
        const __half2 wh = *reinterpret_cast<const __half2*>(&w[u]);
        const float w1 = __low2float(wh);
        const float w2 = __high2float(wh);
        const float2 a0 = __half22float2(*(const __half2*)&ra[u].x);
        const float2 a1 = __half22float2(*(const __half2*)&ra[u].y);
        const float2 c0 = __half22float2(*(const __half2*)&rb[u].x);
        const float2 c1 = __half22float2(*(const __half2*)&rb[u].y);
        acc.x += w1 * a0.x + w2 * c0.x;
        acc.y += w1 * a0.y + w2 * c0.y;
        acc.z += w1 * a1.x + w2 * c1.x;
        acc.w += w1 * a1.y + w2 * c1.y;
    }
}

// Block = 256 threads handles 4 consecutive queries of one batch.
// Phase 1: per-block sample descriptors packed into LDS (uint2: k1|k2<<16, half2 w).
// Phase 2: thread = (qi, h, d4); depth-4 double-buffered gather pipeline.
template <bool FP16>
__global__ __launch_bounds__(256, 4) void spd_kernel(
    const float* __restrict__ value,   // (bs, NK, H, D) fp32
    const __half* __restrict__ vh,     // same, fp16 (workspace), if FP16
    const float* __restrict__ loc,     // (bs, NQ, H, LV, P, 1)
    const float* __restrict__ wts,     // (bs, NQ, H, LV, P)
    float* __restrict__ out)           // (bs, NQ, H*D)
{
    const int tid = threadIdx.x;
    // XCD swizzle: XCD = launched bid % 8; give each XCD one batch's chunk.
    const int vbid = ((blockIdx.x & 7) << 9) | (blockIdx.x >> 3);
    const int bq0 = vbid << 2;                // first flat (b*NQ + q)
    const int b   = bq0 >> 12;                // NQ = 4096

    __shared__ uint2 s_d[32 * LDSS];          // {k1|k2<<16, half2(w1,w2)}

    // ---- Phase 1: precompute sample descriptors ----
    #pragma unroll
    for (int e = 0; e < 4; ++e) {
        const int ent = (e << 8) | tid;       // ent = qi*256 + h*32 + l*8 + p
        const size_t g = (size_t)bq0 * 256 + (size_t)ent;
        const float x_loc = loc[g];
        const float w     = wts[g];

        const int l   = (ent >> 3) & 3;
        const int L   = 16384 >> l;
        const int off = 32768 - (32768 >> l); // 0, 16384, 24576, 28672

        const float x  = x_loc * (float)L - 1.0f;
        const float xf = floorf(x);
        const float lx = x - xf;
        const float hx = 1.0f - lx;
        const int   xl = (int)xf;
        const int   xh = xl + 1;

        const bool ok1 = (xl >= 0) && (xl < L);
        const bool ok2 = (xh >= 0) && (xh < L);
        int c1 = xl < 0 ? 0 : (xl > L - 1 ? L - 1 : xl);
        int c2 = xh < 0 ? 0 : (xh > L - 1 ? L - 1 : xh);
        const float w1 = ok1 ? w * hx : 0.0f;
        const float w2 = ok2 ? w * lx : 0.0f;

        // row = l*8+p (j), col = qi*8+h ; stride 33 -> conflict-free
        const int li = (ent & 31) * LDSS + ((((ent >> 8) & 3) << 3) | ((ent >> 5) & 7));
        __half2 wh = __floats2half2_rn(w1, w2);
        uint2 d;
        d.x = (unsigned)(off + c1) | ((unsigned)(off + c2) << 16);
        d.y = *reinterpret_cast<unsigned*>(&wh);
        s_d[li] = d;
    }
    __syncthreads();

    // ---- Phase 2: pipelined gather + accumulate ----
    const int qi = tid >> 6;         // query within block (one wave per query)
    const int h  = (tid >> 3) & 7;
    const int d4 = tid & 7;          // uint2 slice of D=32 (4 halves)
    const int cb = (qi << 3) | h;
    const unsigned lane = (unsigned)((h << 3) | d4);

    float4 acc = make_float4(0.f, 0.f, 0.f, 0.f);

    if (FP16) {
        const uint2* __restrict__ vb2 =
            (const uint2*)(vh) + (size_t)b * (NK * 64);   // per-batch base

        unsigned wA[4], wB[4];
        uint2 aA[4], bA[4], aB[4], bB[4];

        load4(vb2, s_d, 0, cb, lane, wA, aA, bA);
        load4(vb2, s_d, 4, cb, lane, wB, aB, bB);
        #pragma unroll
        for (int jj = 8; jj < 32; jj += 8) {
            consume4(wA, aA, bA, acc);
            load4(vb2, s_d, jj, cb, lane, wA, aA, bA);
            consume4(wB, aB, bB, acc);
            load4(vb2, s_d, jj + 4, cb, lane, wB, aB, bB);
        }
        consume4(wA, aA, bA, acc);
        consume4(wB, aB, bB, acc);
    } else {
        const float4* __restrict__ vb4 =
            (const float4*)(value) + (size_t)b * (NK * 64);
        #pragma unroll 8
        for (int j = 0; j < 32; ++j) {
            const uint2 d = s_d[j * LDSS + cb];
            const __half2 wh = *reinterpret_cast<const __half2*>(&d.y);
            const float w1 = __low2float(wh);
            const float w2 = __high2float(wh);
            const float4 a = vb4[(size_t)((d.x & 0xffffu) << 6) + lane];
            const float4 c = vb4[(size_t)((d.x >> 16) << 6) + lane];
            acc.x += w1 * a.x + w2 * c.x;
            acc.y += w1 * a.y + w2 * c.y;
            acc.z += w1 * a.z + w2 * c.z;
            acc.w += w1 * a.w + w2 * c.w;
        }
    }

    float4* __restrict__ o4 = (float4*)out;
    o4[(size_t)(bq0 + qi) * 64 + ((h << 3) | d4)] = acc;
}

extern "C" void kernel_launch(void* const* d_in, const int* in_sizes, int n_in,
                              void* d_out, int out_size, void* d_ws, size_t ws_size,
                              hipStream_t stream) {
    const float* value = (const float*)d_in[0];
    const float* loc   = (const float*)d_in[1];
    const float* wts   = (const float*)d_in[2];
    float* out = (float*)d_out;

    const int bs = 4;
    const int blocks = bs * NQ / 4;   // 4096
    const size_t need = (size_t)bs * NK * NH * ND * sizeof(__half);  // ~63 MB

    if (ws_size >= need) {
        const int n8 = bs * NK * NH * ND / 8;  // 8 floats per thread-iter
        cvt_kernel<<<2048, 256, 0, stream>>>(value, (uint4*)d_ws, n8);
        spd_kernel<true><<<blocks, 256, 0, stream>>>(value, (const __half*)d_ws,
                                                     loc, wts, out);
    } else {
        spd_kernel<false><<<blocks, 256, 0, stream>>>(value, nullptr,
                                                      loc, wts, out);
    }
}

// Round 5
// 82.288 us; speedup vs baseline: 1.5366x; 1.5364x over previous
//
#include <hip/hip_runtime.h>
#include <hip/hip_fp16.h>

#define NQ 4096
#define NH 8
#define ND 32
#define NK 30720   // 16384+8192+4096+2048
#define LDSS 33    // padded LDS row stride (conflict-free)

// ---- Pre-pass: value fp32 -> fp16 into workspace (halves gather traffic) ----
__global__ __launch_bounds__(256) void cvt_kernel(const float* __restrict__ v,
                                                  uint4* __restrict__ o, int n8) {
    int i = blockIdx.x * blockDim.x + threadIdx.x;
    const float4* __restrict__ v4 = (const float4*)v;
    for (; i < n8; i += gridDim.x * blockDim.x) {
        const float4 f0 = v4[2 * i];
        const float4 f1 = v4[2 * i + 1];
        __half2 h0 = __floats2half2_rn(f0.x, f0.y);
        __half2 h1 = __floats2half2_rn(f0.z, f0.w);
        __half2 h2 = __floats2half2_rn(f1.x, f1.y);
        __half2 h3 = __floats2half2_rn(f1.z, f1.w);
        uint4 u;
        u.x = *reinterpret_cast<unsigned*>(&h0);
        u.y = *reinterpret_cast<unsigned*>(&h1);
        u.z = *reinterpret_cast<unsigned*>(&h2);
        u.w = *reinterpret_cast<unsigned*>(&h3);
        o[i] = u;
    }
}

// Work partition: 8 groups = (batch, h-half), one per XCD. Each block: 8 queries
// x 4 heads (its half). Per-XCD value footprint = 7.9 MB fp16 (lvl0 4MB ~ L2),
// no cross-XCD duplication of value lines.
// Phase 1: 1024 packed descriptors {k1|k2<<16, half2(w1,w2)} into LDS.
// Phase 2: R2-style load-and-consume gather (lane = q2 x h4 x d4).
template <bool FP16>
__global__ __launch_bounds__(256, 8) void spd_kernel(
    const float* __restrict__ value,   // (bs, NK, H, D) fp32
    const __half* __restrict__ vh,     // same, fp16 (workspace), if FP16
    const float* __restrict__ loc,     // (bs, NQ, H, LV, P, 1)
    const float* __restrict__ wts,     // (bs, NQ, H, LV, P)
    float* __restrict__ out)           // (bs, NQ, H*D)
{
    const int tid = threadIdx.x;
    const int g  = blockIdx.x & 7;     // XCD id = group = b*2 + hh
    const int w  = blockIdx.x >> 3;    // [0,512) within group
    const int b  = g >> 1;
    const int hh = g & 1;              // which half of the 8 heads
    const int q0 = w << 3;             // first of 8 queries

    __shared__ uint2 s_d[32 * LDSS];   // [row=l*8+p][col=q*4+h4]

    // ---- Phase 1: descriptors for 8 queries x 4 heads x 32 taps ----
    const size_t base = ((size_t)(b * NQ + q0) * 8 + hh * 4) * 32;
    #pragma unroll
    for (int e = 0; e < 4; ++e) {
        const int ent = (e << 8) | tid;    // q(3b)|h4(2b)|l(2b)|p(3b)
        const size_t gidx = base + (size_t)(ent >> 7) * 256 + (ent & 127);
        const float x_loc = loc[gidx];
        const float wq    = wts[gidx];

        const int l   = (ent >> 3) & 3;
        const int L   = 16384 >> l;
        const int off = 32768 - (32768 >> l); // 0,16384,24576,28672

        const float x  = x_loc * (float)L - 1.0f;
        const float xf = floorf(x);
        const float lx = x - xf;
        const float hx = 1.0f - lx;
        const int   xl = (int)xf;
        const int   xh = xl + 1;

        const bool ok1 = (xl >= 0) && (xl < L);
        const bool ok2 = (xh >= 0) && (xh < L);
        int c1 = xl < 0 ? 0 : (xl > L - 1 ? L - 1 : xl);
        int c2 = xh < 0 ? 0 : (xh > L - 1 ? L - 1 : xh);
        const float w1 = ok1 ? wq * hx : 0.0f;
        const float w2 = ok2 ? wq * lx : 0.0f;

        const int li = (ent & 31) * LDSS + (ent >> 5);  // row=lp, col=q*4+h4
        __half2 wh = __floats2half2_rn(w1, w2);
        uint2 d;
        d.x = (unsigned)(off + c1) | ((unsigned)(off + c2) << 16);
        d.y = *reinterpret_cast<unsigned*>(&wh);
        s_d[li] = d;
    }
    __syncthreads();

    // ---- Phase 2: gather + accumulate (R2 structure) ----
    const int qi = tid >> 5;                 // query within block [0,8)
    const int cb = tid >> 3;                 // LDS col = q*4+h4 [0,32)
    const int h  = (hh << 2) | ((tid >> 3) & 3);
    const int d4 = tid & 7;
    const unsigned lane = (unsigned)((h << 3) | d4);  // slice within key row

    float4 acc = make_float4(0.f, 0.f, 0.f, 0.f);

    if (FP16) {
        const uint2* __restrict__ vb2 =
            (const uint2*)(vh) + (size_t)b * (NK * 64);   // 64 uint2 per key
        #pragma unroll 16
        for (int j = 0; j < 32; ++j) {
            const uint2 d = s_d[j * LDSS + cb];
            const __half2 wh = *reinterpret_cast<const __half2*>(&d.y);
            const float w1 = __low2float(wh);
            const float w2 = __high2float(wh);
            const uint2 r1 = vb2[((d.x & 0xffffu) << 6) + lane];
            const uint2 r2 = vb2[((d.x >> 16) << 6) + lane];
            const float2 a0 = __half22float2(*(const __half2*)&r1.x);
            const float2 a1 = __half22float2(*(const __half2*)&r1.y);
            const float2 c0 = __half22float2(*(const __half2*)&r2.x);
            const float2 c1 = __half22float2(*(const __half2*)&r2.y);
            acc.x += w1 * a0.x + w2 * c0.x;
            acc.y += w1 * a0.y + w2 * c0.y;
            acc.z += w1 * a1.x + w2 * c1.x;
            acc.w += w1 * a1.y + w2 * c1.y;
        }
    } else {
        const float4* __restrict__ vb4 =
            (const float4*)(value) + (size_t)b * (NK * 64); // 64 float4 per key
        #pragma unroll 16
        for (int j = 0; j < 32; ++j) {
            const uint2 d = s_d[j * LDSS + cb];
            const __half2 wh = *reinterpret_cast<const __half2*>(&d.y);
            const float w1 = __low2float(wh);
            const float w2 = __high2float(wh);
            const float4 a = vb4[(size_t)((d.x & 0xffffu) << 6) + lane];
            const float4 c = vb4[(size_t)((d.x >> 16) << 6) + lane];
            acc.x += w1 * a.x + w2 * c.x;
            acc.y += w1 * a.y + w2 * c.y;
            acc.z += w1 * a.z + w2 * c.z;
            acc.w += w1 * a.w + w2 * c.w;
        }
    }

    float4* __restrict__ o4 = (float4*)out;
    o4[(size_t)(b * NQ + q0 + qi) * 64 + lane] = acc;
}

extern "C" void kernel_launch(void* const* d_in, const int* in_sizes, int n_in,
                              void* d_out, int out_size, void* d_ws, size_t ws_size,
                              hipStream_t stream) {
    const float* value = (const float*)d_in[0];
    const float* loc   = (const float*)d_in[1];
    const float* wts   = (const float*)d_in[2];
    float* out = (float*)d_out;

    const int bs = 4;
    const int blocks = 8 * (NQ / 8);  // 8 groups x 512 = 4096
    const size_t need = (size_t)bs * NK * NH * ND * sizeof(__half);  // ~63 MB

    if (ws_size >= need) {
        const int n8 = bs * NK * NH * ND / 8;  // 8 floats per thread-iter
        cvt_kernel<<<2048, 256, 0, stream>>>(value, (uint4*)d_ws, n8);
        spd_kernel<true><<<blocks, 256, 0, stream>>>(value, (const __half*)d_ws,
                                                     loc, wts, out);
    } else {
        spd_kernel<false><<<blocks, 256, 0, stream>>>(value, nullptr,
                                                      loc, wts, out);
    }
}